// Round 2
// baseline (10.959 us; speedup 1.0000x reference)
//
#include <hip/hip_runtime.h>

// CZ ring on 12 wires is a product of diagonal gates:
//   U[s,s] = (-1)^( sum_{j} bit_j(s) * bit_{(j+1)%12}(s) )
// so reference(x) = D * x with D a +/-1 diagonal: elementwise sign flip.
//
// x is [4096, 1024] row-major float32 -> 2^20 float4 total.
// Latency-bound regime (working set is L2/L3-resident during replay):
// 4 independent float4 per thread for MLP; 1024 blocks x 256 threads.

__global__ __launch_bounds__(256) void czring_sign_kernel(
    const float4* __restrict__ x, float4* __restrict__ out) {
    const unsigned t = blockIdx.x * blockDim.x + threadIdx.x;  // 0 .. 2^18-1
    // 4 coalesced chunks, each 2^18 apart -> every load coalesced per wave
    float4 v0 = x[t];
    float4 v1 = x[t + (1u << 18)];
    float4 v2 = x[t + (2u << 18)];
    float4 v3 = x[t + (3u << 18)];

    // sign for float4 index g: row = g >> 8 (256 float4 per 1024-col row)
    #pragma unroll
    for (int k = 0; k < 4; ++k) {
        unsigned g = t + ((unsigned)k << 18);
        unsigned row = g >> 8;
        unsigned rot = ((row << 1) | (row >> 11)) & 0xFFFu;
        float s = (__popc(row & rot) & 1) ? -1.0f : 1.0f;
        float4* v = (k == 0) ? &v0 : (k == 1) ? &v1 : (k == 2) ? &v2 : &v3;
        v->x *= s; v->y *= s; v->z *= s; v->w *= s;
    }

    out[t] = v0;
    out[t + (1u << 18)] = v1;
    out[t + (2u << 18)] = v2;
    out[t + (3u << 18)] = v3;
}

extern "C" void kernel_launch(void* const* d_in, const int* in_sizes, int n_in,
                              void* d_out, int out_size, void* d_ws, size_t ws_size,
                              hipStream_t stream) {
    const float4* x = (const float4*)d_in[0];
    float4* out = (float4*)d_out;
    const int block = 256;
    const int grid = 1024;  // 1024*256 threads * 4 float4 = 2^20 float4
    czring_sign_kernel<<<grid, block, 0, stream>>>(x, out);
}